// Round 8
// baseline (345.409 us; speedup 1.0000x reference)
//
#include <hip/hip_runtime.h>
#include <hip/hip_bf16.h>
#include <math.h>

#define BB 2
#define TT 2048
#define CC 2048
#define NH 16
#define NKV 4
#define HD 128
#define BT (BB*TT)
#define WINDOW 1024
#define SQKV 3072   // QKV buffer row stride: Q cols 0-2047, K 2048-2559 (V lives only in Vt)

typedef unsigned short u16;
typedef unsigned int u32;
typedef __attribute__((ext_vector_type(8))) short short8;      // 8 bf16 = 4 VGPRs (MFMA A/B frag)
typedef __attribute__((ext_vector_type(8))) unsigned short ushort8;
typedef __attribute__((ext_vector_type(4))) unsigned short ushort4v;
typedef __attribute__((ext_vector_type(2))) unsigned int uint2v;
typedef __attribute__((ext_vector_type(4))) float floatx4;     // 16x16 MFMA C/D frag
typedef __attribute__((ext_vector_type(16))) float floatx16;   // 32x32 MFMA C/D frag

typedef const __attribute__((address_space(1))) u32* gas_ptr;
typedef __attribute__((address_space(3))) u32* las_ptr;

static __device__ __forceinline__ u16 f2bf(float f) {
    unsigned u = __builtin_bit_cast(unsigned, f);
    return (u16)((u + 0x7fffu + ((u >> 16) & 1u)) >> 16);   // RNE
}
static __device__ __forceinline__ float bf2f(u16 v) {
    unsigned u = ((unsigned)v) << 16;
    return __builtin_bit_cast(float, u);
}

// packed f32x2 -> bf16x2 (RNE), low half = lo, high half = hi
static __device__ __forceinline__ u32 cvt_pk_bf16(float lo, float hi) {
    u32 r;
    asm("v_cvt_pk_bf16_f32 %0, %1, %2" : "=v"(r) : "v"(lo), "v"(hi));
    return r;
}

// softcap+exp: exp(50*tanh(s/50)) = exp2( t*(c0 + c1 t^2 + c2 t^4) ), t=s/50 clamped to [-1,1].
static __device__ __forceinline__ float softcap_exp(float s) {
    float t = s * 0.02f;
    t = fmaxf(-1.0f, fminf(1.0f, t));     // v_med3
    float t2 = t * t;
    float e = t * fmaf(t2, fmaf(t2, 9.617967f, -24.044917f), 72.134752f);
    return __builtin_amdgcn_exp2f(e);
}

// ---------------- fused prep: cast x -> bf16 AND all 4 weight transposes, one launch ----------------
// blocks [0, 8192):        cast x (fp32 -> bf16, float4/thread)
// blocks [8192, 12288):    wq^T  -> wqkvT rows 0-2047      (64 x 64 tiles)
// blocks [12288, 13312):   wk^T  -> wqkvT rows 2048-2559   (16 x 64)
// blocks [13312, 14336):   wv^T  -> wqkvT rows 2560-3071   (16 x 64)
// blocks [14336, 18432):   wo^T  -> woT                    (64 x 64)
// All sub-ops independent, BW-bound; fusing removes 4 launch gaps and lets them overlap.
__global__ __launch_bounds__(256) void prep_kernel(const float* __restrict__ x,
                                                   const float* __restrict__ wq,
                                                   const float* __restrict__ wk,
                                                   const float* __restrict__ wv,
                                                   const float* __restrict__ wo,
                                                   u16* __restrict__ xb,
                                                   u16* __restrict__ wqkvT,
                                                   u16* __restrict__ woT) {
    __shared__ u16 tile[32][33];
    int bid = blockIdx.x;
    int tid = threadIdx.x;
    if (bid < 8192) {                              // ---- cast x ----
        int i = bid * 256 + tid;                   // 8192*256 = 2097152 = BT*CC/4 exactly
        floatx4 v = *(const floatx4*)(x + (size_t)i * 4);
        ushort4v o;
        o[0] = f2bf(v[0]); o[1] = f2bf(v[1]); o[2] = f2bf(v[2]); o[3] = f2bf(v[3]);
        *(ushort4v*)(xb + (size_t)i * 4) = o;
        return;
    }
    bid -= 8192;
    const float* in; u16* out; int Cc, bx, by;
    if (bid < 4096)      { in = wq; out = wqkvT;                    Cc = 2048; bx = bid & 63; by = bid >> 6; }
    else if (bid < 5120) { bid -= 4096; in = wk; out = wqkvT + (size_t)2048 * CC; Cc = 512; bx = bid & 15; by = bid >> 4; }
    else if (bid < 6144) { bid -= 5120; in = wv; out = wqkvT + (size_t)2560 * CC; Cc = 512; bx = bid & 15; by = bid >> 4; }
    else                 { bid -= 6144; in = wo; out = woT;         Cc = 2048; bx = bid & 63; by = bid >> 6; }
    const int R = 2048;                            // all weight matrices have 2048 rows
    int c0 = bx * 32, r0 = by * 32;
    int tx = tid & 31, ty = tid >> 5;              // (32, 8)
    #pragma unroll
    for (int i = 0; i < 4; i++) {
        int r = r0 + ty + i * 8;
        tile[ty + i * 8][tx] = f2bf(in[(size_t)r * Cc + c0 + tx]);
    }
    __syncthreads();
    #pragma unroll
    for (int i = 0; i < 4; i++) {
        int c = c0 + ty + i * 8;
        out[(size_t)c * R + r0 + tx] = tile[tx][ty + i * 8];
    }
}

// ---------------- RoPE, single launch for Q and K, trig computed per-block into LDS ----------------
// grid BT, 320 threads: tid 0-255 = Q (16 heads x 16 thr), tid 256-319 = K (4 heads x 16 thr).
// Each thread owns pair (d=j0..j0+3, d+64) exclusively: no cross-thread hazard, in-place.
// 64 sincosf per block into LDS replaces the global trig table (same arithmetic: exp2f+sincosf).
__global__ __launch_bounds__(320) void rope_kernel(u16* __restrict__ buf) {
    __shared__ float tab[128];                     // [j][{cos,sin}]
    int bt = blockIdx.x;
    int t = bt & (TT - 1);
    int tid = threadIdx.x;
    if (tid < 64) {
        float inv = exp2f(-0.20762050593046f * (float)tid);   // 10000^(-j/64)
        float s, c;
        sincosf((float)t * inv, &s, &c);
        tab[tid * 2] = c; tab[tid * 2 + 1] = s;
    }
    __syncthreads();
    bool isQ = tid < 256;
    int loc = isQ ? tid : tid - 256;
    int h = loc >> 4;
    int j0 = (loc & 15) * 4;
    float scale = isQ ? 0.08838834764831845f : 1.0f;
    u16* p = buf + (size_t)bt * SQKV + (isQ ? 0 : 2048) + h * HD + j0;
    ushort4v lo = *(const ushort4v*)(p);
    ushort4v hi = *(const ushort4v*)(p + 64);
    ushort4v olo, ohi;
    #pragma unroll
    for (int i = 0; i < 4; i++) {
        float c = tab[(j0 + i) * 2], s = tab[(j0 + i) * 2 + 1];
        float x1 = bf2f(lo[i]), x2 = bf2f(hi[i]);
        olo[i] = f2bf((x1 * c - x2 * s) * scale);
        ohi[i] = f2bf((x2 * c + x1 * s) * scale);
    }
    *(ushort4v*)(p) = olo;
    *(ushort4v*)(p + 64) = ohi;
}

// ---------------- m97-style GEMM, frag-major LDS: C[M][N] = A[M][K] * Bt[N][K]^T ----------------
// Proven 2-barrier schedule (R2/R7); LDS layout upgraded to FRAG-MAJOR (proven zero-conflict
// R3-R5): 8 A-groups + 8 B-groups of 1KB, group f = one 16x16x32 MFMA fragment
// (lane l: row f*16+(l&15), k (l>>4)*8..+8). Staging pre-permutes the per-lane GLOBAL source;
// LDS dest is wave-uniform + lane*16B (DMA rule). Every ds_read_b128 is lane-consecutive 16B
// => zero bank conflicts; MFMA inputs bit-identical to the old [128][32] layout.
// OMODE: 0 = bf16 out, 1 = f32 out, 2 = QKV: V cols (>=2560, block-uniform) -> Vt transposed.
template <int OMODE>
__global__ __launch_bounds__(256) void gemm128_kernel(const u16* __restrict__ A,
                                                      const u16* __restrict__ Bt,
                                                      void* __restrict__ Cout,
                                                      u16* __restrict__ Vt,
                                                      int M, int N, int K) {
    __shared__ alignas(16) u16 As[4096];   // 8 frag-groups x 1KB
    __shared__ alignas(16) u16 Bs[4096];
    int tid = threadIdx.x;
    int w = tid >> 6, lane = tid & 63, quad = lane >> 4, ln = lane & 15;
    int m0 = blockIdx.y * 128;
    int n0 = blockIdx.x * 128;
    int wm = (w >> 1) * 64;
    int wn = (w & 1) * 64;

    // staging: wave w covers groups g = j*4 + w (j=0..3); g<8: A-frag group g, g>=8: B group g-8
    const u16* gsrc[4];
    u16* ldstp[4];
    #pragma unroll
    for (int j = 0; j < 4; j++) {
        int g = j * 4 + w;
        int f = g & 7;
        const u16* base = (g < 8) ? (A + (size_t)m0 * K) : (Bt + (size_t)n0 * K);
        gsrc[j] = base + (size_t)(f * 16 + ln) * K + quad * 8;
        ldstp[j] = (g < 8 ? As : Bs) + f * 512;    // wave-uniform base; HW adds lane*16B
    }

    floatx4 acc[4][4] = {};

    for (int k0 = 0; k0 < K; k0 += 32) {
        __syncthreads();
        #pragma unroll
        for (int j = 0; j < 4; j++)
            __builtin_amdgcn_global_load_lds((gas_ptr)(gsrc[j] + k0), (las_ptr)ldstp[j], 16, 0, 0);
        __syncthreads();

        short8 af[4], bf[4];
        #pragma unroll
        for (int mt = 0; mt < 4; mt++)
            af[mt] = *(const short8*)(As + ((w >> 1) * 4 + mt) * 512 + lane * 8);
        #pragma unroll
        for (int nt = 0; nt < 4; nt++)
            bf[nt] = *(const short8*)(Bs + ((w & 1) * 4 + nt) * 512 + lane * 8);
        #pragma unroll
        for (int mt = 0; mt < 4; mt++)
            #pragma unroll
            for (int nt = 0; nt < 4; nt++)
                acc[mt][nt] = __builtin_amdgcn_mfma_f32_16x16x32_bf16(af[mt], bf[nt], acc[mt][nt], 0, 0, 0);
    }

    if (OMODE == 2 && n0 >= 2560) {
        // whole block is V (2560 = 20*128): write transposed to Vt[b][c][t]
        int b = m0 >> 11;                          // TT = 2048, 128 | 2048 => uniform per block
        int tb = (m0 & (TT - 1)) + wm;
        #pragma unroll
        for (int mt = 0; mt < 4; mt++)
          #pragma unroll
          for (int nt = 0; nt < 4; nt++) {
              int c = n0 + wn + nt * 16 + ln - 2560;
              int t0 = tb + mt * 16 + quad * 4;
              ushort4v o;
              #pragma unroll
              for (int r = 0; r < 4; r++) o[r] = f2bf(acc[mt][nt][r]);
              *(ushort4v*)(Vt + (size_t)b * (NKV * HD) * TT + (size_t)c * TT + t0) = o;
          }
    } else {
        #pragma unroll
        for (int mt = 0; mt < 4; mt++)
          #pragma unroll
          for (int nt = 0; nt < 4; nt++)
            #pragma unroll
            for (int r = 0; r < 4; r++) {
                size_t row = m0 + wm + mt * 16 + quad * 4 + r;
                size_t col = n0 + wn + nt * 16 + ln;
                float v = acc[mt][nt][r];
                if (OMODE == 1) ((float*)Cout)[row * N + col] = v;
                else            ((u16*)Cout)[row * N + col] = f2bf(v);
            }
    }
}

// ---------------- flash attention v3: shared K/V tiles, 128-query blocks ----------------
// Block = 128 queries x (b,h), 4 waves each owning 32 queries. All waves iterate the SAME key
// tiles; K/V staged in LDS once per block via global_load_lds (16 x 1KB DMA, 4 per wave),
// double-buffered with one-tile-ahead prefetch. Raw s_barrier + counted vmcnt(4).
// LDS layout = read order: every ds_read_b128 is lane-linear over a contiguous 1KB group =>
// conflict-free. In-register softmax via sigma-permuted K rows + cvt_pk P-pack:
//   sigma(m) = (m&3) + 4*bit3(m) + 8*bit2(m) + 16*bit4(m)
//   S^T reg r holds key s0 + (r&3) + 4*((r>>2)&1) + 8*hi + 16*(r>>3), col q = ln.
__global__ __launch_bounds__(256, 2) void attn_kernel(const u16* __restrict__ QKV,
                                                      const u16* __restrict__ Vt,
                                                      u16* __restrict__ Enc) {
    // buf[2] x { K: 8KB (groups ks=0..7, 1KB each) | V: 8KB (groups g=dt*2+half) } = 32KB
    __shared__ alignas(16) u16 pool[2 * 8192];

    int tid = threadIdx.x;
    int w = tid >> 6, lane = tid & 63, hi = lane >> 5, ln = lane & 31;
    int hi8 = hi * 8;

    int qb = (15 - (int)blockIdx.x) * 128;      // long blocks first
    int bh = blockIdx.y;
    int b = bh >> 4, h = bh & 15, kh = h >> 2;
    int qw = qb + w * 32;                        // this wave's query base

    // Q B-frag [n=q=ln][k=hi*8 + ks*16 + j]
    short8 qf[8];
    {
        const u16* qptr = QKV + (size_t)(b * TT + qw + ln) * SQKV + h * HD + hi8;
        #pragma unroll
        for (int ks = 0; ks < 8; ks++) qf[ks] = *(const short8*)(qptr + ks * 16);
    }

    // ---- DMA source setup: wave w issues groups [w*4, w*4+4) of {K0..7, V0..7} ----
    int sig = (ln & 3) + (((ln >> 3) & 1) << 2) + (((ln >> 2) & 1) << 3) + ((ln >> 4) << 4);
    bool isK = (w < 2);
    const u16* dsrc[4];
    int ldst[4];                                 // u16 offset within a 16KB buffer
    #pragma unroll
    for (int i = 0; i < 4; i++) {
        if (isK) {
            int ks = w * 4 + i;
            dsrc[i] = QKV + (size_t)(b * TT + sig) * SQKV + 2048 + kh * HD + ks * 16 + hi8;
            ldst[i] = ks * 512;
        } else {
            int g = (w - 2) * 4 + i;
            dsrc[i] = Vt + (size_t)((b * NKV + kh) * HD + (g >> 1) * 32 + ln) * TT + (g & 1) * 16 + hi8;
            ldst[i] = 4096 + g * 512;
        }
    }
    size_t addmul = isK ? (size_t)SQKV : (size_t)1;

    floatx16 O0 = {}, O1 = {}, O2 = {}, O3 = {};   // O^T d-tiles: D[m=d][n=q]
    float lacc = 0.0f;

    int S_LO = qb - WINDOW; if (S_LO < 0) S_LO = 0;
    int nt = (qb + 128 - S_LO) >> 5;

    auto issue = [&](int t) {
        int s0 = S_LO + t * 32;
        u16* base = pool + (t & 1) * 8192;
        size_t add = (size_t)s0 * addmul;
        #pragma unroll
        for (int i = 0; i < 4; i++)
            __builtin_amdgcn_global_load_lds((gas_ptr)(dsrc[i] + add), (las_ptr)(base + ldst[i]), 16, 0, 0);
    };

    issue(0);
    for (int t = 0; t < nt; ++t) {
        // barrier A: all waves done reading buf[(t+1)&1] (= tile t-1's buffer)
        __builtin_amdgcn_sched_barrier(0);
        __builtin_amdgcn_s_barrier();
        __builtin_amdgcn_sched_barrier(0);
        if (t + 1 < nt) {
            issue(t + 1);
            __builtin_amdgcn_sched_barrier(0);
            __builtin_amdgcn_s_waitcnt(0x0F74);   // vmcnt(4): own tile-t DMAs landed, t+1 in flight
        } else {
            __builtin_amdgcn_s_waitcnt(0x0F70);   // vmcnt(0): last tile, drain all
        }
        __builtin_amdgcn_sched_barrier(0);
        __builtin_amdgcn_s_barrier();             // barrier B: ALL waves' tile-t data in LDS
        __builtin_amdgcn_sched_barrier(0);

        int s0 = S_LO + t * 32;
        if (s0 > qw + 31 || s0 + 31 < qw - WINDOW) continue;   // tile outside this wave's window

        const u16* Kb = pool + (t & 1) * 8192;
        const u16* Vb = Kb + 4096;

        // ---- S^T = K Q^T (rows = sigma-permuted keys, cols = q) ----
        floatx16 S = {};
        #pragma unroll
        for (int ks = 0; ks < 8; ks++) {
            short8 kf = *(const short8*)(Kb + ks * 512 + lane * 8);   // lane-linear: conflict-free
            S = __builtin_amdgcn_mfma_f32_32x32x16_bf16(kf, qf[ks], S, 0, 0, 0);
        }

        // ---- softcap + exp (+ mask only on edge tiles), in place ----
        bool full = (s0 + 31 <= qw) && (s0 >= qw + 31 - WINDOW);
        if (full) {
            #pragma unroll
            for (int r = 0; r < 16; r++) S[r] = softcap_exp(S[r]);
        } else {
            int tq = qw + ln;
            #pragma unroll
            for (int r = 0; r < 16; r++) {
                int s = s0 + (r & 3) + (((r >> 2) & 1) << 2) + hi8 + ((r >> 3) << 4);
                bool good = (s <= tq) && (s >= tq - WINDOW);
                S[r] = good ? softcap_exp(S[r]) : 0.0f;
            }
        }

        // ---- own-half l accumulation (tree) ----
        lacc += ((((S[0] + S[1]) + (S[2] + S[3])) + ((S[4] + S[5]) + (S[6] + S[7])))
               + (((S[8] + S[9]) + (S[10] + S[11])) + ((S[12] + S[13]) + (S[14] + S[15]))));

        // ---- pack P -> bf16 B-frags (already frag-ordered thanks to sigma) ----
        u32 w0a = cvt_pk_bf16(S[0],  S[1]),  w0b = cvt_pk_bf16(S[2],  S[3]);
        u32 w0c = cvt_pk_bf16(S[4],  S[5]),  w0d = cvt_pk_bf16(S[6],  S[7]);
        u32 w1a = cvt_pk_bf16(S[8],  S[9]),  w1b = cvt_pk_bf16(S[10], S[11]);
        u32 w1c = cvt_pk_bf16(S[12], S[13]), w1d = cvt_pk_bf16(S[14], S[15]);
        typedef __attribute__((ext_vector_type(4))) unsigned int u32x4t;
        u32x4t pw0 = { w0a, w0b, w0c, w0d };
        u32x4t pw1 = { w1a, w1b, w1c, w1d };
        short8 pf0 = __builtin_bit_cast(short8, pw0);
        short8 pf1 = __builtin_bit_cast(short8, pw1);

        // ---- O^T += V^T P^T (V frags lane-linear 1KB reads: conflict-free) ----
        #pragma unroll
        for (int dt = 0; dt < 4; dt++) {
            short8 vf0 = *(const short8*)(Vb + (dt * 2 + 0) * 512 + lane * 8);
            short8 vf1 = *(const short8*)(Vb + (dt * 2 + 1) * 512 + lane * 8);
            floatx16* Od = (dt == 0) ? &O0 : (dt == 1) ? &O1 : (dt == 2) ? &O2 : &O3;
            *Od = __builtin_amdgcn_mfma_f32_32x32x16_bf16(vf0, pf0, *Od, 0, 0, 0);
            *Od = __builtin_amdgcn_mfma_f32_32x32x16_bf16(vf1, pf1, *Od, 0, 0, 0);
        }
    }

    __syncthreads();   // drain everything; staging LDS is now free for the epilogue

    // ---- epilogue: normalize, transpose O^T -> O via wave-private 2KB LDS bounce ----
    lacc += __shfl_xor(lacc, 32);                  // fold the other key-half (same q on lane^32)
    float inv = __builtin_amdgcn_rcpf(lacc);
    u16* ep = pool + w * 1024;                     // [32 q][32 d] bf16 per dt pass
    const floatx16* Os[4] = { &O0, &O1, &O2, &O3 };
    #pragma unroll
    for (int dt = 0; dt < 4; dt++) {
        #pragma unroll
        for (int g = 0; g < 4; g++) {
            // reg r=g*4+i -> d_local = i + 8g + 4hi, col q=ln
            float a0 = (*Os[dt])[g * 4 + 0] * inv, a1 = (*Os[dt])[g * 4 + 1] * inv;
            float a2 = (*Os[dt])[g * 4 + 2] * inv, a3 = (*Os[dt])[g * 4 + 3] * inv;
            uint2v pk;
            pk[0] = cvt_pk_bf16(a0, a1);
            pk[1] = cvt_pk_bf16(a2, a3);
            *(uint2v*)(ep + ln * 32 + g * 8 + hi * 4) = pk;   // same-wave DS pipe is in-order
        }
        ushort8 r0 = *(const ushort8*)(ep + ln * 32 + hi * 16);
        ushort8 r1 = *(const ushort8*)(ep + ln * 32 + hi * 16 + 8);
        u16* dst = Enc + (size_t)(b * TT + qw + ln) * (NH * HD) + h * HD + dt * 32 + hi * 16;
        *(ushort8*)dst = r0;
        *(ushort8*)(dst + 8) = r1;
    }
}

extern "C" void kernel_launch(void* const* d_in, const int* in_sizes, int n_in,
                              void* d_out, int out_size, void* d_ws, size_t ws_size,
                              hipStream_t stream) {
    const float* x  = (const float*)d_in[0];
    const float* wq = (const float*)d_in[1];
    const float* wk = (const float*)d_in[2];
    const float* wv = (const float*)d_in[3];
    const float* wo = (const float*)d_in[4];
    float* out = (float*)d_out;

    char* ws = (char*)d_ws;
    size_t off = 0;
    auto alloc = [&](size_t bytes) -> void* {
        void* p = ws + off;
        off += (bytes + 255) & ~(size_t)255;
        return p;
    };
    u16* xb    = (u16*)alloc((size_t)BT * CC * 2);
    u16* wqkvT = (u16*)alloc((size_t)SQKV * CC * 2);   // rows: Wq^T 0-2047, Wk^T 2048-2559, Wv^T 2560-3071
    u16* woT   = (u16*)alloc((size_t)CC * CC * 2);
    u16* QKVb  = (u16*)alloc((size_t)BT * SQKV * 2);   // [4096][3072] (V region unused)
    u16* VtT   = (u16*)alloc((size_t)BT * NKV * HD * 2); // [B][NKV*HD][T]
    u16* Enc   = (u16*)alloc((size_t)BT * NH * HD * 2);

    // 1) fused prep: cast x + all weight transposes (one launch, 18432 blocks)
    prep_kernel<<<18432, 256, 0, stream>>>(x, wq, wk, wv, wo, xb, wqkvT, woT);

    // 2) merged QKV projection (N=3072, 768 blocks); V columns written directly to VtT transposed
    gemm128_kernel<2><<<dim3(SQKV / 128, BT / 128), 256, 0, stream>>>(xb, wqkvT, QKVb, VtT, BT, SQKV, CC);

    // 3) RoPE, single launch (Q scaled, K unscaled), trig in LDS
    rope_kernel<<<BT, 320, 0, stream>>>(QKVb);

    // 4) flash attention: 512 blocks (16 query-blocks x 32 bh), shared K/V tiles per block
    attn_kernel<<<dim3(16, 32), 256, 0, stream>>>(QKVb, VtT, Enc);

    // 5) output projection (fp32 out)
    gemm128_kernel<1><<<dim3(CC / 128, BT / 128), 256, 0, stream>>>(Enc, woT, out, nullptr, BT, CC, CC);
}

// Round 9
// 302.765 us; speedup vs baseline: 1.1408x; 1.1408x over previous
//
#include <hip/hip_runtime.h>
#include <hip/hip_bf16.h>
#include <math.h>

#define BB 2
#define TT 2048
#define CC 2048
#define NH 16
#define NKV 4
#define HD 128
#define BT (BB*TT)
#define WINDOW 1024
#define SQKV 3072   // QKV buffer row stride: Q cols 0-2047, K 2048-2559 (V lives only in Vt)

typedef unsigned short u16;
typedef unsigned int u32;
typedef __attribute__((ext_vector_type(8))) short short8;      // 8 bf16 = 4 VGPRs (MFMA A/B frag)
typedef __attribute__((ext_vector_type(8))) unsigned short ushort8;
typedef __attribute__((ext_vector_type(4))) unsigned short ushort4v;
typedef __attribute__((ext_vector_type(2))) unsigned int uint2v;
typedef __attribute__((ext_vector_type(4))) float floatx4;     // 16x16 MFMA C/D frag
typedef __attribute__((ext_vector_type(16))) float floatx16;   // 32x32 MFMA C/D frag

typedef const __attribute__((address_space(1))) u32* gas_ptr;
typedef __attribute__((address_space(3))) u32* las_ptr;

static __device__ __forceinline__ u16 f2bf(float f) {
    unsigned u = __builtin_bit_cast(unsigned, f);
    return (u16)((u + 0x7fffu + ((u >> 16) & 1u)) >> 16);   // RNE
}
static __device__ __forceinline__ float bf2f(u16 v) {
    unsigned u = ((unsigned)v) << 16;
    return __builtin_bit_cast(float, u);
}

// packed f32x2 -> bf16x2 (RNE), low half = lo, high half = hi
static __device__ __forceinline__ u32 cvt_pk_bf16(float lo, float hi) {
    u32 r;
    asm("v_cvt_pk_bf16_f32 %0, %1, %2" : "=v"(r) : "v"(lo), "v"(hi));
    return r;
}

// softcap+exp: exp(50*tanh(s/50)) = exp2( t*(c0 + c1 t^2 + c2 t^4) ), t=s/50 clamped to [-1,1].
static __device__ __forceinline__ float softcap_exp(float s) {
    float t = s * 0.02f;
    t = fmaxf(-1.0f, fminf(1.0f, t));     // v_med3
    float t2 = t * t;
    float e = t * fmaf(t2, fmaf(t2, 9.617967f, -24.044917f), 72.134752f);
    return __builtin_amdgcn_exp2f(e);
}

// ---------------- fused prep: cast x -> bf16 AND all 4 weight transposes, one launch ----------------
// blocks [0, 8192):        cast x (fp32 -> bf16, float4/thread)
// blocks [8192, 12288):    wq^T  -> wqkvT rows 0-2047      (64 x 64 tiles)
// blocks [12288, 13312):   wk^T  -> wqkvT rows 2048-2559   (16 x 64)
// blocks [13312, 14336):   wv^T  -> wqkvT rows 2560-3071   (16 x 64)
// blocks [14336, 18432):   wo^T  -> woT                    (64 x 64)
// All sub-ops independent, BW-bound; fusing removes 4 launch gaps (measured ~29us with rope fusion, R8).
__global__ __launch_bounds__(256) void prep_kernel(const float* __restrict__ x,
                                                   const float* __restrict__ wq,
                                                   const float* __restrict__ wk,
                                                   const float* __restrict__ wv,
                                                   const float* __restrict__ wo,
                                                   u16* __restrict__ xb,
                                                   u16* __restrict__ wqkvT,
                                                   u16* __restrict__ woT) {
    __shared__ u16 tile[32][33];
    int bid = blockIdx.x;
    int tid = threadIdx.x;
    if (bid < 8192) {                              // ---- cast x ----
        int i = bid * 256 + tid;                   // 8192*256 = 2097152 = BT*CC/4 exactly
        floatx4 v = *(const floatx4*)(x + (size_t)i * 4);
        ushort4v o;
        o[0] = f2bf(v[0]); o[1] = f2bf(v[1]); o[2] = f2bf(v[2]); o[3] = f2bf(v[3]);
        *(ushort4v*)(xb + (size_t)i * 4) = o;
        return;
    }
    bid -= 8192;
    const float* in; u16* out; int Cc, bx, by;
    if (bid < 4096)      { in = wq; out = wqkvT;                    Cc = 2048; bx = bid & 63; by = bid >> 6; }
    else if (bid < 5120) { bid -= 4096; in = wk; out = wqkvT + (size_t)2048 * CC; Cc = 512; bx = bid & 15; by = bid >> 4; }
    else if (bid < 6144) { bid -= 5120; in = wv; out = wqkvT + (size_t)2560 * CC; Cc = 512; bx = bid & 15; by = bid >> 4; }
    else                 { bid -= 6144; in = wo; out = woT;         Cc = 2048; bx = bid & 63; by = bid >> 6; }
    const int R = 2048;                            // all weight matrices have 2048 rows
    int c0 = bx * 32, r0 = by * 32;
    int tx = tid & 31, ty = tid >> 5;              // (32, 8)
    #pragma unroll
    for (int i = 0; i < 4; i++) {
        int r = r0 + ty + i * 8;
        tile[ty + i * 8][tx] = f2bf(in[(size_t)r * Cc + c0 + tx]);
    }
    __syncthreads();
    #pragma unroll
    for (int i = 0; i < 4; i++) {
        int c = c0 + ty + i * 8;
        out[(size_t)c * R + r0 + tx] = tile[tx][ty + i * 8];
    }
}

// ---------------- RoPE, single launch for Q and K, trig computed per-block into LDS ----------------
// grid BT, 320 threads: tid 0-255 = Q (16 heads x 16 thr), tid 256-319 = K (4 heads x 16 thr).
// Each thread owns pair (d=j0..j0+3, d+64) exclusively: no cross-thread hazard, in-place.
// 64 sincosf per block into LDS replaces the global trig table (same arithmetic: exp2f+sincosf).
__global__ __launch_bounds__(320) void rope_kernel(u16* __restrict__ buf) {
    __shared__ float tab[128];                     // [j][{cos,sin}]
    int bt = blockIdx.x;
    int t = bt & (TT - 1);
    int tid = threadIdx.x;
    if (tid < 64) {
        float inv = exp2f(-0.20762050593046f * (float)tid);   // 10000^(-j/64)
        float s, c;
        sincosf((float)t * inv, &s, &c);
        tab[tid * 2] = c; tab[tid * 2 + 1] = s;
    }
    __syncthreads();
    bool isQ = tid < 256;
    int loc = isQ ? tid : tid - 256;
    int h = loc >> 4;
    int j0 = (loc & 15) * 4;
    float scale = isQ ? 0.08838834764831845f : 1.0f;
    u16* p = buf + (size_t)bt * SQKV + (isQ ? 0 : 2048) + h * HD + j0;
    ushort4v lo = *(const ushort4v*)(p);
    ushort4v hi = *(const ushort4v*)(p + 64);
    ushort4v olo, ohi;
    #pragma unroll
    for (int i = 0; i < 4; i++) {
        float c = tab[(j0 + i) * 2], s = tab[(j0 + i) * 2 + 1];
        float x1 = bf2f(lo[i]), x2 = bf2f(hi[i]);
        olo[i] = f2bf((x1 * c - x2 * s) * scale);
        ohi[i] = f2bf((x2 * c + x1 * s) * scale);
    }
    *(ushort4v*)(p) = olo;
    *(ushort4v*)(p + 64) = ohi;
}

// ---------------- m97-style GEMM: C[M][N] = A[M][K] * Bt[N][K]^T (bf16 in, fp32 acc) ----------------
// R7-proven version (75.5us QKV). Row-major [128][32] LDS; staging keeps 4-lane 64B-contiguous
// global reads (quarter-wave coalescing). NOTE (R8 lesson): frag-major LDS with row-per-lane
// global sources zeroed bank conflicts but broke quarter-wave coalescing -> +40% time. The ~6M
// conflict cycles here are 2-way-aliasing class (nearly free); do NOT "fix" them at the cost of
// the global access pattern.
// OMODE: 0 = bf16 out, 1 = f32 out, 2 = QKV: V cols (>=2560, block-uniform) -> Vt transposed.
template <int OMODE>
__global__ __launch_bounds__(256) void gemm128_kernel(const u16* __restrict__ A,
                                                      const u16* __restrict__ Bt,
                                                      void* __restrict__ Cout,
                                                      u16* __restrict__ Vt,
                                                      int M, int N, int K) {
    __shared__ alignas(16) u16 As[128 * 32];   // row-major [128][32], NO padding (lds-dma layout)
    __shared__ alignas(16) u16 Bs[128 * 32];
    int tid = threadIdx.x;
    int w = tid >> 6, lane = tid & 63, quad = lane >> 4, ln = lane & 15;
    int m0 = blockIdx.y * 128;
    int n0 = blockIdx.x * 128;
    int wm = (w >> 1) * 64;
    int wn = (w & 1) * 64;

    int o0 = (w * 2) * 1024 + lane * 16;
    int row0 = o0 >> 6, kc0 = (o0 & 63) >> 4;
    int o1 = o0 + 1024;
    int row1 = o1 >> 6, kc1 = (o1 & 63) >> 4;
    const u16* gA0 = A  + (size_t)(m0 + row0) * K + kc0 * 8;
    const u16* gA1 = A  + (size_t)(m0 + row1) * K + kc1 * 8;
    const u16* gB0 = Bt + (size_t)(n0 + row0) * K + kc0 * 8;
    const u16* gB1 = Bt + (size_t)(n0 + row1) * K + kc1 * 8;
    u16* lA0 = As + (w * 2) * 512;
    u16* lA1 = As + (w * 2 + 1) * 512;
    u16* lB0 = Bs + (w * 2) * 512;
    u16* lB1 = Bs + (w * 2 + 1) * 512;

    floatx4 acc[4][4] = {};

    for (int k0 = 0; k0 < K; k0 += 32) {
        __syncthreads();
        __builtin_amdgcn_global_load_lds((gas_ptr)(gA0 + k0), (las_ptr)lA0, 16, 0, 0);
        __builtin_amdgcn_global_load_lds((gas_ptr)(gA1 + k0), (las_ptr)lA1, 16, 0, 0);
        __builtin_amdgcn_global_load_lds((gas_ptr)(gB0 + k0), (las_ptr)lB0, 16, 0, 0);
        __builtin_amdgcn_global_load_lds((gas_ptr)(gB1 + k0), (las_ptr)lB1, 16, 0, 0);
        __syncthreads();

        short8 af[4], bf[4];
        #pragma unroll
        for (int mt = 0; mt < 4; mt++)
            af[mt] = *(const short8*)(As + (wm + mt * 16 + ln) * 32 + quad * 8);
        #pragma unroll
        for (int nt = 0; nt < 4; nt++)
            bf[nt] = *(const short8*)(Bs + (wn + nt * 16 + ln) * 32 + quad * 8);
        #pragma unroll
        for (int mt = 0; mt < 4; mt++)
            #pragma unroll
            for (int nt = 0; nt < 4; nt++)
                acc[mt][nt] = __builtin_amdgcn_mfma_f32_16x16x32_bf16(af[mt], bf[nt], acc[mt][nt], 0, 0, 0);
    }

    if (OMODE == 2 && n0 >= 2560) {
        // whole block is V (2560 = 20*128): write transposed to Vt[b][c][t]
        int b = m0 >> 11;                          // TT = 2048, 128 | 2048 => uniform per block
        int tb = (m0 & (TT - 1)) + wm;
        #pragma unroll
        for (int mt = 0; mt < 4; mt++)
          #pragma unroll
          for (int nt = 0; nt < 4; nt++) {
              int c = n0 + wn + nt * 16 + ln - 2560;
              int t0 = tb + mt * 16 + quad * 4;
              ushort4v o;
              #pragma unroll
              for (int r = 0; r < 4; r++) o[r] = f2bf(acc[mt][nt][r]);
              *(ushort4v*)(Vt + (size_t)b * (NKV * HD) * TT + (size_t)c * TT + t0) = o;
          }
    } else {
        #pragma unroll
        for (int mt = 0; mt < 4; mt++)
          #pragma unroll
          for (int nt = 0; nt < 4; nt++)
            #pragma unroll
            for (int r = 0; r < 4; r++) {
                size_t row = m0 + wm + mt * 16 + quad * 4 + r;
                size_t col = n0 + wn + nt * 16 + ln;
                float v = acc[mt][nt][r];
                if (OMODE == 1) ((float*)Cout)[row * N + col] = v;
                else            ((u16*)Cout)[row * N + col] = f2bf(v);
            }
    }
}

// ---------------- flash attention v3: shared K/V tiles, 128-query blocks ----------------
// Block = 128 queries x (b,h), 4 waves each owning 32 queries. All waves iterate the SAME key
// tiles; K/V staged in LDS once per block via global_load_lds (16 x 1KB DMA, 4 per wave),
// double-buffered with one-tile-ahead prefetch. Raw s_barrier + counted vmcnt(4).
// LDS layout = read order: every ds_read_b128 is lane-linear over a contiguous 1KB group =>
// conflict-free. In-register softmax via sigma-permuted K rows + cvt_pk P-pack:
//   sigma(m) = (m&3) + 4*bit3(m) + 8*bit2(m) + 16*bit4(m)
//   S^T reg r holds key s0 + (r&3) + 4*((r>>2)&1) + 8*hi + 16*(r>>3), col q = ln.
__global__ __launch_bounds__(256, 2) void attn_kernel(const u16* __restrict__ QKV,
                                                      const u16* __restrict__ Vt,
                                                      u16* __restrict__ Enc) {
    // buf[2] x { K: 8KB (groups ks=0..7, 1KB each) | V: 8KB (groups g=dt*2+half) } = 32KB
    __shared__ alignas(16) u16 pool[2 * 8192];

    int tid = threadIdx.x;
    int w = tid >> 6, lane = tid & 63, hi = lane >> 5, ln = lane & 31;
    int hi8 = hi * 8;

    int qb = (15 - (int)blockIdx.x) * 128;      // long blocks first
    int bh = blockIdx.y;
    int b = bh >> 4, h = bh & 15, kh = h >> 2;
    int qw = qb + w * 32;                        // this wave's query base

    // Q B-frag [n=q=ln][k=hi*8 + ks*16 + j]
    short8 qf[8];
    {
        const u16* qptr = QKV + (size_t)(b * TT + qw + ln) * SQKV + h * HD + hi8;
        #pragma unroll
        for (int ks = 0; ks < 8; ks++) qf[ks] = *(const short8*)(qptr + ks * 16);
    }

    // ---- DMA source setup: wave w issues groups [w*4, w*4+4) of {K0..7, V0..7} ----
    int sig = (ln & 3) + (((ln >> 3) & 1) << 2) + (((ln >> 2) & 1) << 3) + ((ln >> 4) << 4);
    bool isK = (w < 2);
    const u16* dsrc[4];
    int ldst[4];                                 // u16 offset within a 16KB buffer
    #pragma unroll
    for (int i = 0; i < 4; i++) {
        if (isK) {
            int ks = w * 4 + i;
            dsrc[i] = QKV + (size_t)(b * TT + sig) * SQKV + 2048 + kh * HD + ks * 16 + hi8;
            ldst[i] = ks * 512;
        } else {
            int g = (w - 2) * 4 + i;
            dsrc[i] = Vt + (size_t)((b * NKV + kh) * HD + (g >> 1) * 32 + ln) * TT + (g & 1) * 16 + hi8;
            ldst[i] = 4096 + g * 512;
        }
    }
    size_t addmul = isK ? (size_t)SQKV : (size_t)1;

    floatx16 O0 = {}, O1 = {}, O2 = {}, O3 = {};   // O^T d-tiles: D[m=d][n=q]
    float lacc = 0.0f;

    int S_LO = qb - WINDOW; if (S_LO < 0) S_LO = 0;
    int nt = (qb + 128 - S_LO) >> 5;

    auto issue = [&](int t) {
        int s0 = S_LO + t * 32;
        u16* base = pool + (t & 1) * 8192;
        size_t add = (size_t)s0 * addmul;
        #pragma unroll
        for (int i = 0; i < 4; i++)
            __builtin_amdgcn_global_load_lds((gas_ptr)(dsrc[i] + add), (las_ptr)(base + ldst[i]), 16, 0, 0);
    };

    issue(0);
    for (int t = 0; t < nt; ++t) {
        // barrier A: all waves done reading buf[(t+1)&1] (= tile t-1's buffer)
        __builtin_amdgcn_sched_barrier(0);
        __builtin_amdgcn_s_barrier();
        __builtin_amdgcn_sched_barrier(0);
        if (t + 1 < nt) {
            issue(t + 1);
            __builtin_amdgcn_sched_barrier(0);
            __builtin_amdgcn_s_waitcnt(0x0F74);   // vmcnt(4): own tile-t DMAs landed, t+1 in flight
        } else {
            __builtin_amdgcn_s_waitcnt(0x0F70);   // vmcnt(0): last tile, drain all
        }
        __builtin_amdgcn_sched_barrier(0);
        __builtin_amdgcn_s_barrier();             // barrier B: ALL waves' tile-t data in LDS
        __builtin_amdgcn_sched_barrier(0);

        int s0 = S_LO + t * 32;
        if (s0 > qw + 31 || s0 + 31 < qw - WINDOW) continue;   // tile outside this wave's window

        const u16* Kb = pool + (t & 1) * 8192;
        const u16* Vb = Kb + 4096;

        // ---- S^T = K Q^T (rows = sigma-permuted keys, cols = q) ----
        floatx16 S = {};
        #pragma unroll
        for (int ks = 0; ks < 8; ks++) {
            short8 kf = *(const short8*)(Kb + ks * 512 + lane * 8);   // lane-linear: conflict-free
            S = __builtin_amdgcn_mfma_f32_32x32x16_bf16(kf, qf[ks], S, 0, 0, 0);
        }

        // ---- softcap + exp (+ mask only on edge tiles), in place ----
        bool full = (s0 + 31 <= qw) && (s0 >= qw + 31 - WINDOW);
        if (full) {
            #pragma unroll
            for (int r = 0; r < 16; r++) S[r] = softcap_exp(S[r]);
        } else {
            int tq = qw + ln;
            #pragma unroll
            for (int r = 0; r < 16; r++) {
                int s = s0 + (r & 3) + (((r >> 2) & 1) << 2) + hi8 + ((r >> 3) << 4);
                bool good = (s <= tq) && (s >= tq - WINDOW);
                S[r] = good ? softcap_exp(S[r]) : 0.0f;
            }
        }

        // ---- own-half l accumulation (tree) ----
        lacc += ((((S[0] + S[1]) + (S[2] + S[3])) + ((S[4] + S[5]) + (S[6] + S[7])))
               + (((S[8] + S[9]) + (S[10] + S[11])) + ((S[12] + S[13]) + (S[14] + S[15]))));

        // ---- pack P -> bf16 B-frags (already frag-ordered thanks to sigma) ----
        u32 w0a = cvt_pk_bf16(S[0],  S[1]),  w0b = cvt_pk_bf16(S[2],  S[3]);
        u32 w0c = cvt_pk_bf16(S[4],  S[5]),  w0d = cvt_pk_bf16(S[6],  S[7]);
        u32 w1a = cvt_pk_bf16(S[8],  S[9]),  w1b = cvt_pk_bf16(S[10], S[11]);
        u32 w1c = cvt_pk_bf16(S[12], S[13]), w1d = cvt_pk_bf16(S[14], S[15]);
        typedef __attribute__((ext_vector_type(4))) unsigned int u32x4t;
        u32x4t pw0 = { w0a, w0b, w0c, w0d };
        u32x4t pw1 = { w1a, w1b, w1c, w1d };
        short8 pf0 = __builtin_bit_cast(short8, pw0);
        short8 pf1 = __builtin_bit_cast(short8, pw1);

        // ---- O^T += V^T P^T (V frags lane-linear 1KB reads: conflict-free) ----
        #pragma unroll
        for (int dt = 0; dt < 4; dt++) {
            short8 vf0 = *(const short8*)(Vb + (dt * 2 + 0) * 512 + lane * 8);
            short8 vf1 = *(const short8*)(Vb + (dt * 2 + 1) * 512 + lane * 8);
            floatx16* Od = (dt == 0) ? &O0 : (dt == 1) ? &O1 : (dt == 2) ? &O2 : &O3;
            *Od = __builtin_amdgcn_mfma_f32_32x32x16_bf16(vf0, pf0, *Od, 0, 0, 0);
            *Od = __builtin_amdgcn_mfma_f32_32x32x16_bf16(vf1, pf1, *Od, 0, 0, 0);
        }
    }

    __syncthreads();   // drain everything; staging LDS is now free for the epilogue

    // ---- epilogue: normalize, transpose O^T -> O via wave-private 2KB LDS bounce ----
    lacc += __shfl_xor(lacc, 32);                  // fold the other key-half (same q on lane^32)
    float inv = __builtin_amdgcn_rcpf(lacc);
    u16* ep = pool + w * 1024;                     // [32 q][32 d] bf16 per dt pass
    const floatx16* Os[4] = { &O0, &O1, &O2, &O3 };
    #pragma unroll
    for (int dt = 0; dt < 4; dt++) {
        #pragma unroll
        for (int g = 0; g < 4; g++) {
            // reg r=g*4+i -> d_local = i + 8g + 4hi, col q=ln
            float a0 = (*Os[dt])[g * 4 + 0] * inv, a1 = (*Os[dt])[g * 4 + 1] * inv;
            float a2 = (*Os[dt])[g * 4 + 2] * inv, a3 = (*Os[dt])[g * 4 + 3] * inv;
            uint2v pk;
            pk[0] = cvt_pk_bf16(a0, a1);
            pk[1] = cvt_pk_bf16(a2, a3);
            *(uint2v*)(ep + ln * 32 + g * 8 + hi * 4) = pk;   // same-wave DS pipe is in-order
        }
        ushort8 r0 = *(const ushort8*)(ep + ln * 32 + hi * 16);
        ushort8 r1 = *(const ushort8*)(ep + ln * 32 + hi * 16 + 8);
        u16* dst = Enc + (size_t)(b * TT + qw + ln) * (NH * HD) + h * HD + dt * 32 + hi * 16;
        *(ushort8*)dst = r0;
        *(ushort8*)(dst + 8) = r1;
    }
}

extern "C" void kernel_launch(void* const* d_in, const int* in_sizes, int n_in,
                              void* d_out, int out_size, void* d_ws, size_t ws_size,
                              hipStream_t stream) {
    const float* x  = (const float*)d_in[0];
    const float* wq = (const float*)d_in[1];
    const float* wk = (const float*)d_in[2];
    const float* wv = (const float*)d_in[3];
    const float* wo = (const float*)d_in[4];
    float* out = (float*)d_out;

    char* ws = (char*)d_ws;
    size_t off = 0;
    auto alloc = [&](size_t bytes) -> void* {
        void* p = ws + off;
        off += (bytes + 255) & ~(size_t)255;
        return p;
    };
    u16* xb    = (u16*)alloc((size_t)BT * CC * 2);
    u16* wqkvT = (u16*)alloc((size_t)SQKV * CC * 2);   // rows: Wq^T 0-2047, Wk^T 2048-2559, Wv^T 2560-3071
    u16* woT   = (u16*)alloc((size_t)CC * CC * 2);
    u16* QKVb  = (u16*)alloc((size_t)BT * SQKV * 2);   // [4096][3072] (V region unused)
    u16* VtT   = (u16*)alloc((size_t)BT * NKV * HD * 2); // [B][NKV*HD][T]
    u16* Enc   = (u16*)alloc((size_t)BT * NH * HD * 2);

    // 1) fused prep: cast x + all weight transposes (one launch, 18432 blocks)
    prep_kernel<<<18432, 256, 0, stream>>>(x, wq, wk, wv, wo, xb, wqkvT, woT);

    // 2) merged QKV projection (N=3072, 768 blocks); V columns written directly to VtT transposed
    gemm128_kernel<2><<<dim3(SQKV / 128, BT / 128), 256, 0, stream>>>(xb, wqkvT, QKVb, VtT, BT, SQKV, CC);

    // 3) RoPE, single launch (Q scaled, K unscaled), trig in LDS
    rope_kernel<<<BT, 320, 0, stream>>>(QKVb);

    // 4) flash attention: 512 blocks (16 query-blocks x 32 bh), shared K/V tiles per block
    attn_kernel<<<dim3(16, 32), 256, 0, stream>>>(QKVb, VtT, Enc);

    // 5) output projection (fp32 out)
    gemm128_kernel<1><<<dim3(CC / 128, BT / 128), 256, 0, stream>>>(Enc, woT, out, nullptr, BT, CC, CC);
}